// Round 9
// baseline (187.219 us; speedup 1.0000x reference)
//
#include <hip/hip_runtime.h>
#include <hip/hip_fp16.h>

// Problem geometry (fixed by reference)
#define WINS 7
#define H 160
#define W 160
#define DD 96
#define HO 154          // H - WINS + 1
#define WO 154
#define DOUT 90
#define CSTRIDE (H*W*DD)   // per-(b,c) channel stride

// Tile: 8x8x24 outputs, all 4 classes sequentially per block.
#define TH 8
#define TW 8
#define TD 24
#define IH 14            // TH + WINS - 1
#define IW 14
#define NCOL (IH * IW)   // 196
#define IDS 32           // staged halfs per column (fallback path only)
#define NDP 15           // dd-pairs per column
#define HTILES 20
#define WTILES 20
#define DTILES 4

// R9: packed-pair LDS layouts, same R8 structure (direct-global A, 2 bars/cl).
//  - sA01 = uint2 slot[(ih*8+wo)*15+dp] holding {S_m,S_p} as 2xhalf2 (b64);
//    sA2v = half2 plane. A-writes 24->16 ops, B-reads 30->20.
//  - sb01/sb2v same packing: B-writes 12->8, C-reads 18->12.
//  - All b64 naturally 8B-aligned (slot arrays). Bank maps (enumerated):
//    b64 ops land on even banks ~2-way (free, m136); C <=3-way on a few.
//  - LDS total 31,696 B < 32 KiB. Cross-round residency ratios (R0 0.66,
//    R7 0.68 vs R3/R5/R8 0.51 at exactly 32,768) suggest the exact-32K fit
//    effectively caps at 4 blocks; ~1 KiB slack should restore a true
//    5-block fit -> +25% issue capacity. This is the hypothesis under test.

struct alignas(8) Half4 { __half x, y, z, w; };

static __device__ __forceinline__ __half2 u2h(unsigned int a) {
    __half2 r; __builtin_memcpy(&r, &a, 4); return r;
}
static __device__ __forceinline__ unsigned int h2u(__half2 v) {
    unsigned int r; __builtin_memcpy(&r, &v, 4); return r;
}
// p = max(v,0) per half; m = (sign clear) ? 1.0h : 0.0h per half.
static __device__ __forceinline__ void pmask(__half2 v, __half2& p, __half2& m) {
    const unsigned int bits = h2u(v);
    const unsigned int neg  = bits & 0x80008000u;
    const unsigned int full = (neg >> 15) * 0xFFFFu;          // 0xFFFF where negative
    p = u2h(bits & ~full);
    m = u2h(((~bits >> 15) & 0x00010001u) * 0x3C00u);         // 1.0h where sign clear
}

__device__ __forceinline__ float sval(float c0, float c1, float c2) {
    // c0=S_m, c1=S_tm, c2=S_t2m over the 343-voxel window; t = m?sigmoid:0.5
    const float S_t  = c1 + 0.5f  * (343.0f - c0);
    const float S_t2 = c2 + 0.25f * (343.0f - c0);
    const float inv  = 1.0f / 343.0f;
    const float ux   = S_t  * inv;
    const float uy   = c0   * inv;
    const float uxx  = S_t2 * inv;
    const float uxy  = c1   * inv;
    const float covn = 49.0f / 48.0f;   // WIN^2/(WIN^2-1)
    const float cc   = 0.00045f;        // (0.03*data_range)^2/2, data_range==1
    const float vx  = covn * (uxx - ux * ux);
    const float vy  = covn * (uy  - uy * uy);
    const float vxy = covn * (uxy - ux * uy);
    return (vxy + cc) * __builtin_amdgcn_rcpf(vx * vy + cc);   // den >= ~3e-4
}

// Pre-pass: v = (y==c ? +sigmoid(x) : -sigmoid(x)) as f16, one value per
// (channel, voxel). Also zeroes acc (replaces the hipMemsetAsync dispatch).
__global__ __launch_bounds__(256)
void sigmoid_prepass(const float* __restrict__ x,
                     const int* __restrict__ y,
                     __half* __restrict__ xs,
                     double* __restrict__ acc) {
    if (blockIdx.x == 0 && blockIdx.y == 0 && threadIdx.x == 0) acc[0] = 0.0;
    const int b  = blockIdx.y;
    const int qv = blockIdx.x * 256 + threadIdx.x;    // 0..614399
    const int off = 4 * qv;
    const int4 yv = *(const int4*)(y + (size_t)b * CSTRIDE + off);
#pragma unroll
    for (int c = 0; c < 4; c++) {
        const size_t xo = ((size_t)(b * 4 + c)) * CSTRIDE + off;
        const float4 xv = *(const float4*)(x + xo);
        const float s0 = 1.0f / (1.0f + __expf(-xv.x));
        const float s1 = 1.0f / (1.0f + __expf(-xv.y));
        const float s2 = 1.0f / (1.0f + __expf(-xv.z));
        const float s3 = 1.0f / (1.0f + __expf(-xv.w));
        Half4 hv;
        hv.x = __float2half((yv.x == c) ? s0 : -s0);
        hv.y = __float2half((yv.y == c) ? s1 : -s1);
        hv.z = __float2half((yv.z == c) ? s2 : -s2);
        hv.w = __float2half((yv.w == c) ? s3 : -s3);
        *(Half4*)(xs + xo) = hv;
    }
}

// (256,5): 5-block/CU LDS target (31,696 B with slack below 32 KiB).
template <bool PRE>
__global__ __launch_bounds__(256, 5)
void structure_loss_main(const float* __restrict__ x,
                         const int* __restrict__ y,
                         const __half* __restrict__ xs,
                         double* __restrict__ acc) {
    // W-window sums: planes {S_m,S_p} packed in uint2 slots, plane S_q half2.
    __shared__ uint2   sA01[IH * TW * NDP];   // 13,440 B
    __shared__ __half2 sA2v[IH * TW * NDP];   //  6,720 B
    // H-window sums, same packing.
    __shared__ uint2   sb01[TH * TW * NDP];   //  7,680 B
    __shared__ __half2 sb2v[TH * TW * NDP];   //  3,840 B
    // fallback-only staging (PRE: degenerate size)
    __shared__ __half vsF[PRE ? 2 : NCOL * IDS];
    __shared__ unsigned int yb[PRE ? 1 : NCOL * 2];
    __shared__ float wsum[4];

    const int dt = blockIdx.x;                 // 0..3
    const int wt = blockIdx.y;                 // 0..19
    const int z  = blockIdx.z;                 // 0..39 = b*HTILES + ht
    const int b  = z / HTILES;
    const int ht = z - b * HTILES;

    const int h0 = ht * TH, w0 = wt * TW;
    const int d0 = dt * TD;                          // output base: 0,24,48,72
    const int dstage = (dt == DTILES - 1) ? 64 : d0; // staged window base
    const int doff = d0 - dstage;                    // 0 or 8 (uniform)
    const int odmax = min(TD, DOUT - d0);            // 24,24,24,18
    const int* yc = y + (size_t)b * (size_t)CSTRIDE;
    const int t = threadIdx.x;

    // ---- Hoisted role math ----
    // A role: 15-lane contiguous dp runs -> coalesced global reads.
    const bool actA = (t < IH * NDP);          // 210
    const int  ihA  = t / NDP, dpA = t - ihA * NDP;
    const int  sA_  = min(doff + 2 * dpA, IDS - 2);      // <= 30
    const int  hA   = min(h0 + ihA, H - 1);
    const int  wmax = min(IW - 1, W - 1 - w0);           // 13 (7 at wt=19)
    const int  gb0  = (hA * W + w0) * DD + dstage + sA_;
    int goff[IW];
#pragma unroll
    for (int iw = 0; iw < IW; iw++) goff[iw] = gb0 + min(iw, wmax) * DD;
    const int  slA0 = ihA * (TW * NDP) + dpA;            // wo-stride NDP
    // B role:
    const bool actB = (t < 2 * TW * NDP);      // 240
    const int  rB   = t / NDP, dpB = t - rB * NDP;
    const int  woB  = rB & 7, ho0B = (rB >> 3) * 4;      // 0 or 4
    const int  slB0 = (ho0B * TW + woB) * NDP + dpB;     // k-stride TW*NDP
    // C role:
    const int  dqC  = t & 3, woC = (t >> 2) & 7, hoC = t >> 5;
    const bool actC = (h0 + hoC < HO) && (w0 + woC < WO);
    const int  slC0 = (hoC * TW + woC) * NDP + 3 * dqC;  // k: +1, 6 slots

    // ---- Fallback staging lambda (plain vsF layout; perf irrelevant) ----
    auto stageF = [&](int cc) {
        const float* xc = x + ((size_t)b * 4 + cc) * (size_t)CSTRIDE;
#pragma unroll
        for (int k = 0; k < 7; k++) {
            const int i = t + 256 * k;
            if (i < NCOL * 8) {
                const int col = i >> 3, q = i & 7;
                const int ih = col / IW, iw = col - ih * IW;
                const int h = min(h0 + ih, H - 1);
                const int w = min(w0 + iw, W - 1);
                const int dbase = dstage + 4 * q;   // always in-bounds
                const float4 xv = *(const float4*)(xc + (h * W + w) * DD + dbase);
                const unsigned int pk = yb[col * 2 + (q >> 2)] >> (8 * (q & 3));
                const float s0 = 1.0f / (1.0f + __expf(-xv.x));
                const float s1 = 1.0f / (1.0f + __expf(-xv.y));
                const float s2 = 1.0f / (1.0f + __expf(-xv.z));
                const float s3 = 1.0f / (1.0f + __expf(-xv.w));
                Half4 hv;
                hv.x = __float2half(((int)((pk >> 0) & 3u) == cc) ? s0 : -s0);
                hv.y = __float2half(((int)((pk >> 2) & 3u) == cc) ? s1 : -s1);
                hv.z = __float2half(((int)((pk >> 4) & 3u) == cc) ? s2 : -s2);
                hv.w = __float2half(((int)((pk >> 6) & 3u) == cc) ? s3 : -s3);
                *(Half4*)&vsF[col * IDS + 4 * q] = hv;
            }
        }
    };

    if (!PRE) {
        // ---- stage y tile 2-bit packed (fallback only) ----
        for (int i = t; i < NCOL * 2; i += 256) {
            const int col = i >> 1, hf = i & 1;
            const int ih = col / IW, iw = col - ih * IW;
            const int h = min(h0 + ih, H - 1);
            const int w = min(w0 + iw, W - 1);
            const size_t cb = (size_t)(h * W + w) * DD;
            const int dstart = dstage + 16 * hf;     // always in-bounds (<=80)
            unsigned int pk = 0u;
#pragma unroll
            for (int j3 = 0; j3 < 4; j3++) {
                const int4 yv = *(const int4*)(yc + cb + dstart + 4 * j3);
                pk |= (unsigned)(yv.x & 3) << (2 * (4 * j3 + 0));
                pk |= (unsigned)(yv.y & 3) << (2 * (4 * j3 + 1));
                pk |= (unsigned)(yv.z & 3) << (2 * (4 * j3 + 2));
                pk |= (unsigned)(yv.w & 3) << (2 * (4 * j3 + 3));
            }
            yb[i] = pk;
        }
        __syncthreads();
    }

    float lsum = 0.f;

    for (int cl = 0; cl < 4; cl++) {
        if (!PRE) {
            stageF(cl);
            __syncthreads();   // vsF(cl) ready (fallback only)
        }

        // ---- Phase A: direct-global W-window. 210 items (ih,dp) ----
        if (actA) {
            __half2 v2[IW];
            if (PRE) {
                const __half* xcl = xs + (size_t)(4 * b + cl) * (size_t)CSTRIDE;
#pragma unroll
                for (int iw = 0; iw < IW; iw++)
                    v2[iw] = *(const __half2*)(xcl + goff[iw]);
            } else {
#pragma unroll
                for (int iw = 0; iw < IW; iw++)
                    v2[iw] = *(const __half2*)&vsF[(ihA * IW + iw) * IDS + sA_];
            }
            const __half2 z2 = __float2half2_rn(0.f);
            __half2 sm = z2, sp = z2, sq = z2;
#pragma unroll
            for (int iw = 0; iw < WINS; iw++) {
                __half2 p, m;
                pmask(v2[iw], p, m);
                sm = __hadd2(sm, m);
                sp = __hadd2(sp, p);
                sq = __hfma2(p, v2[iw], sq);
            }
            int o = slA0;
            sA01[o] = make_uint2(h2u(sm), h2u(sp));
            sA2v[o] = sq;
#pragma unroll
            for (int wo = 1; wo < TW; wo++) {
                const __half2 a = v2[wo + 6], bb = v2[wo - 1];
                __half2 pa, ma, pb, mb;
                pmask(a, pa, ma);
                pmask(bb, pb, mb);
                sm = __hadd2(sm, __hsub2(ma, mb));
                sp = __hadd2(sp, __hsub2(pa, pb));
                sq = __hadd2(sq, __hsub2(__hmul2(pa, a), __hmul2(pb, bb)));
                o += NDP;
                sA01[o] = make_uint2(h2u(sm), h2u(sp));
                sA2v[o] = sq;
            }
        }
        __syncthreads();   // barA: sA ready; C(cl-1) sb-reads retired

        // ---- Phase B: H-window. 240 items ----
        if (actB) {
            __half2 a0[10], a1[10], a2[10];
#pragma unroll
            for (int k = 0; k < 10; k++) {
                const int idx = slB0 + k * (TW * NDP);
                const uint2 v01 = sA01[idx];
                a0[k] = u2h(v01.x);
                a1[k] = u2h(v01.y);
                a2[k] = sA2v[idx];
            }
            __half2 s0 = a0[0], s1 = a1[0], s2 = a2[0];
#pragma unroll
            for (int k = 1; k < WINS; k++) {
                s0 = __hadd2(s0, a0[k]);
                s1 = __hadd2(s1, a1[k]);
                s2 = __hadd2(s2, a2[k]);
            }
            int o = slB0;
            sb01[o] = make_uint2(h2u(s0), h2u(s1));
            sb2v[o] = s2;
#pragma unroll
            for (int k = 1; k < 4; k++) {
                s0 = __hadd2(s0, __hsub2(a0[k + 6], a0[k - 1]));
                s1 = __hadd2(s1, __hsub2(a1[k + 6], a1[k - 1]));
                s2 = __hadd2(s2, __hsub2(a2[k + 6], a2[k - 1]));
                o += TW * NDP;
                sb01[o] = make_uint2(h2u(s0), h2u(s1));
                sb2v[o] = s2;
            }
        }
        __syncthreads();   // barB: sb ready; B sA-reads retired before next A

        // ---- Phase C: D-window, 6 outputs per thread (ho,wo,dq) ----
        if (actC) {
            float b0[12], b1[12], b2[12];
#pragma unroll
            for (int k = 0; k < 6; k++) {
                const uint2 v01 = sb01[slC0 + k];
                float2 f;
                f = __half22float2(u2h(v01.x));
                b0[2 * k] = f.x; b0[2 * k + 1] = f.y;
                f = __half22float2(u2h(v01.y));
                b1[2 * k] = f.x; b1[2 * k + 1] = f.y;
                f = __half22float2(sb2v[slC0 + k]);
                b2[2 * k] = f.x; b2[2 * k + 1] = f.y;
            }
            float s0 = 0.f, s1 = 0.f, s2 = 0.f;
#pragma unroll
            for (int k = 0; k < WINS; k++) { s0 += b0[k]; s1 += b1[k]; s2 += b2[k]; }
            const int od0 = 6 * dqC;
#pragma unroll
            for (int k = 0; k < 6; k++) {
                if (k > 0) {
                    s0 += b0[k + 6] - b0[k - 1];
                    s1 += b1[k + 6] - b1[k - 1];
                    s2 += b2[k + 6] - b2[k - 1];
                }
                if (od0 + k < odmax) lsum += sval(s0, s1, s2);
            }
        }
        // no trailing barrier: next barA separates C's sb-reads from B(cl+1)
    }

    // wave(64) shuffle reduce, then cross-wave via LDS, one atomic per block
#pragma unroll
    for (int off = 32; off > 0; off >>= 1) lsum += __shfl_down(lsum, off, 64);
    const int wave = t >> 6;
    if ((t & 63) == 0) wsum[wave] = lsum;
    __syncthreads();
    if (t == 0) {
        const float s = wsum[0] + wsum[1] + wsum[2] + wsum[3];
        atomicAdd(acc, (double)s);
    }
}

__global__ void structure_loss_finalize(const double* __restrict__ acc,
                                        float* __restrict__ out) {
    out[0] = 1.0f - (float)(acc[0] / 17075520.0);   // 8*154*154*90
}

extern "C" void kernel_launch(void* const* d_in, const int* in_sizes, int n_in,
                              void* d_out, int out_size, void* d_ws, size_t ws_size,
                              hipStream_t stream) {
    const float* x = (const float*)d_in[0];
    const int*   y = (const int*)d_in[1];
    double* acc = (double*)d_ws;
    __half* xs = (__half*)((char*)d_ws + 16);

    const size_t need = 16 + (size_t)8 * CSTRIDE * sizeof(__half);   // ~39.3 MB
    dim3 grid(DTILES, WTILES, 2 * HTILES);   // (4, 20, 40) = 3,200 blocks

    if (ws_size >= need) {
        // prepass zeroes acc -> 3 dispatches total
        sigmoid_prepass<<<dim3(2400, 2), 256, 0, stream>>>(x, y, xs, acc);
        structure_loss_main<true><<<grid, 256, 0, stream>>>(x, y, xs, acc);
    } else {
        (void)hipMemsetAsync(d_ws, 0, sizeof(double), stream);
        structure_loss_main<false><<<grid, 256, 0, stream>>>(x, y, xs, acc);
    }
    structure_loss_finalize<<<1, 1, 0, stream>>>(acc, (float*)d_out);
}

// Round 10
// 187.069 us; speedup vs baseline: 1.0008x; 1.0008x over previous
//
#include <hip/hip_runtime.h>
#include <hip/hip_fp16.h>

// Problem geometry (fixed by reference)
#define WINS 7
#define H 160
#define W 160
#define DD 96
#define HO 154          // H - WINS + 1
#define WO 154
#define DOUT 90
#define CSTRIDE (H*W*DD)   // per-(b,c) channel stride

// Tile: 8x8x24 outputs, all 4 classes sequentially per block.
#define TH 8
#define TW 8
#define TD 24
#define IH 14            // TH + WINS - 1
#define IW 14
#define NCOL (IH * IW)   // 196
#define IDS 32           // staged halfs per column (fallback path only)
#define NDP 15           // dd-pairs per column
#define HTILES 20
#define WTILES 20
#define DTILES 4

// R10 = R9 + re-applied T14 issue-early prefetch (the R5 win that the R8
// rewrite dropped): Phase A's 14 global half2 loads for class cl+1 are
// issued immediately after class cl's A-window consumes v2 -- they land
// during barA+B+barB+C (~1500cy) instead of stalling at the loop head.
// Class loop fully unrolled -> static v2 indexing (no scratch).
// R9 kept: packed-pair LDS (sA01/sA2v, sb01/sb2v), 31,696 B < 32 KiB
// -> true 5-block/CU fit (occupancy 32->38.4% measured), direct-global A,
// 2 barriers/class.

struct alignas(8) Half4 { __half x, y, z, w; };

static __device__ __forceinline__ __half2 u2h(unsigned int a) {
    __half2 r; __builtin_memcpy(&r, &a, 4); return r;
}
static __device__ __forceinline__ unsigned int h2u(__half2 v) {
    unsigned int r; __builtin_memcpy(&r, &v, 4); return r;
}
// p = max(v,0) per half; m = (sign clear) ? 1.0h : 0.0h per half.
static __device__ __forceinline__ void pmask(__half2 v, __half2& p, __half2& m) {
    const unsigned int bits = h2u(v);
    const unsigned int neg  = bits & 0x80008000u;
    const unsigned int full = (neg >> 15) * 0xFFFFu;          // 0xFFFF where negative
    p = u2h(bits & ~full);
    m = u2h(((~bits >> 15) & 0x00010001u) * 0x3C00u);         // 1.0h where sign clear
}

__device__ __forceinline__ float sval(float c0, float c1, float c2) {
    // c0=S_m, c1=S_tm, c2=S_t2m over the 343-voxel window; t = m?sigmoid:0.5
    const float S_t  = c1 + 0.5f  * (343.0f - c0);
    const float S_t2 = c2 + 0.25f * (343.0f - c0);
    const float inv  = 1.0f / 343.0f;
    const float ux   = S_t  * inv;
    const float uy   = c0   * inv;
    const float uxx  = S_t2 * inv;
    const float uxy  = c1   * inv;
    const float covn = 49.0f / 48.0f;   // WIN^2/(WIN^2-1)
    const float cc   = 0.00045f;        // (0.03*data_range)^2/2, data_range==1
    const float vx  = covn * (uxx - ux * ux);
    const float vy  = covn * (uy  - uy * uy);
    const float vxy = covn * (uxy - ux * uy);
    return (vxy + cc) * __builtin_amdgcn_rcpf(vx * vy + cc);   // den >= ~3e-4
}

// Pre-pass: v = (y==c ? +sigmoid(x) : -sigmoid(x)) as f16, one value per
// (channel, voxel). Also zeroes acc (replaces the hipMemsetAsync dispatch).
__global__ __launch_bounds__(256)
void sigmoid_prepass(const float* __restrict__ x,
                     const int* __restrict__ y,
                     __half* __restrict__ xs,
                     double* __restrict__ acc) {
    if (blockIdx.x == 0 && blockIdx.y == 0 && threadIdx.x == 0) acc[0] = 0.0;
    const int b  = blockIdx.y;
    const int qv = blockIdx.x * 256 + threadIdx.x;    // 0..614399
    const int off = 4 * qv;
    const int4 yv = *(const int4*)(y + (size_t)b * CSTRIDE + off);
#pragma unroll
    for (int c = 0; c < 4; c++) {
        const size_t xo = ((size_t)(b * 4 + c)) * CSTRIDE + off;
        const float4 xv = *(const float4*)(x + xo);
        const float s0 = 1.0f / (1.0f + __expf(-xv.x));
        const float s1 = 1.0f / (1.0f + __expf(-xv.y));
        const float s2 = 1.0f / (1.0f + __expf(-xv.z));
        const float s3 = 1.0f / (1.0f + __expf(-xv.w));
        Half4 hv;
        hv.x = __float2half((yv.x == c) ? s0 : -s0);
        hv.y = __float2half((yv.y == c) ? s1 : -s1);
        hv.z = __float2half((yv.z == c) ? s2 : -s2);
        hv.w = __float2half((yv.w == c) ? s3 : -s3);
        *(Half4*)(xs + xo) = hv;
    }
}

// (256,5): 5-block/CU LDS fit (31,696 B).
template <bool PRE>
__global__ __launch_bounds__(256, 5)
void structure_loss_main(const float* __restrict__ x,
                         const int* __restrict__ y,
                         const __half* __restrict__ xs,
                         double* __restrict__ acc) {
    // W-window sums: planes {S_m,S_p} packed in uint2 slots, plane S_q half2.
    __shared__ uint2   sA01[IH * TW * NDP];   // 13,440 B
    __shared__ __half2 sA2v[IH * TW * NDP];   //  6,720 B
    // H-window sums, same packing.
    __shared__ uint2   sb01[TH * TW * NDP];   //  7,680 B
    __shared__ __half2 sb2v[TH * TW * NDP];   //  3,840 B
    // fallback-only staging (PRE: degenerate size)
    __shared__ __half vsF[PRE ? 2 : NCOL * IDS];
    __shared__ unsigned int yb[PRE ? 1 : NCOL * 2];
    __shared__ float wsum[4];

    const int dt = blockIdx.x;                 // 0..3
    const int wt = blockIdx.y;                 // 0..19
    const int z  = blockIdx.z;                 // 0..39 = b*HTILES + ht
    const int b  = z / HTILES;
    const int ht = z - b * HTILES;

    const int h0 = ht * TH, w0 = wt * TW;
    const int d0 = dt * TD;                          // output base: 0,24,48,72
    const int dstage = (dt == DTILES - 1) ? 64 : d0; // staged window base
    const int doff = d0 - dstage;                    // 0 or 8 (uniform)
    const int odmax = min(TD, DOUT - d0);            // 24,24,24,18
    const int* yc = y + (size_t)b * (size_t)CSTRIDE;
    const int t = threadIdx.x;

    // ---- Hoisted role math ----
    // A role: 15-lane contiguous dp runs -> coalesced global reads.
    const bool actA = (t < IH * NDP);          // 210
    const int  ihA  = t / NDP, dpA = t - ihA * NDP;
    const int  sA_  = min(doff + 2 * dpA, IDS - 2);      // <= 30
    const int  hA   = min(h0 + ihA, H - 1);
    const int  wmax = min(IW - 1, W - 1 - w0);           // 13 (7 at wt=19)
    const int  gb0  = (hA * W + w0) * DD + dstage + sA_;
    int goff[IW];
#pragma unroll
    for (int iw = 0; iw < IW; iw++) goff[iw] = gb0 + min(iw, wmax) * DD;
    const int  slA0 = ihA * (TW * NDP) + dpA;            // wo-stride NDP
    // B role:
    const bool actB = (t < 2 * TW * NDP);      // 240
    const int  rB   = t / NDP, dpB = t - rB * NDP;
    const int  woB  = rB & 7, ho0B = (rB >> 3) * 4;      // 0 or 4
    const int  slB0 = (ho0B * TW + woB) * NDP + dpB;     // k-stride TW*NDP
    // C role:
    const int  dqC  = t & 3, woC = (t >> 2) & 7, hoC = t >> 5;
    const bool actC = (h0 + hoC < HO) && (w0 + woC < WO);
    const int  slC0 = (hoC * TW + woC) * NDP + 3 * dqC;  // k: +1, 6 slots

    // ---- Fallback staging lambda (plain vsF layout; perf irrelevant) ----
    auto stageF = [&](int cc) {
        const float* xc = x + ((size_t)b * 4 + cc) * (size_t)CSTRIDE;
#pragma unroll
        for (int k = 0; k < 7; k++) {
            const int i = t + 256 * k;
            if (i < NCOL * 8) {
                const int col = i >> 3, q = i & 7;
                const int ih = col / IW, iw = col - ih * IW;
                const int h = min(h0 + ih, H - 1);
                const int w = min(w0 + iw, W - 1);
                const int dbase = dstage + 4 * q;   // always in-bounds
                const float4 xv = *(const float4*)(xc + (h * W + w) * DD + dbase);
                const unsigned int pk = yb[col * 2 + (q >> 2)] >> (8 * (q & 3));
                const float s0 = 1.0f / (1.0f + __expf(-xv.x));
                const float s1 = 1.0f / (1.0f + __expf(-xv.y));
                const float s2 = 1.0f / (1.0f + __expf(-xv.z));
                const float s3 = 1.0f / (1.0f + __expf(-xv.w));
                Half4 hv;
                hv.x = __float2half(((int)((pk >> 0) & 3u) == cc) ? s0 : -s0);
                hv.y = __float2half(((int)((pk >> 2) & 3u) == cc) ? s1 : -s1);
                hv.z = __float2half(((int)((pk >> 4) & 3u) == cc) ? s2 : -s2);
                hv.w = __float2half(((int)((pk >> 6) & 3u) == cc) ? s3 : -s3);
                *(Half4*)&vsF[col * IDS + 4 * q] = hv;
            }
        }
    };

    if (!PRE) {
        // ---- stage y tile 2-bit packed (fallback only) ----
        for (int i = t; i < NCOL * 2; i += 256) {
            const int col = i >> 1, hf = i & 1;
            const int ih = col / IW, iw = col - ih * IW;
            const int h = min(h0 + ih, H - 1);
            const int w = min(w0 + iw, W - 1);
            const size_t cb = (size_t)(h * W + w) * DD;
            const int dstart = dstage + 16 * hf;     // always in-bounds (<=80)
            unsigned int pk = 0u;
#pragma unroll
            for (int j3 = 0; j3 < 4; j3++) {
                const int4 yv = *(const int4*)(yc + cb + dstart + 4 * j3);
                pk |= (unsigned)(yv.x & 3) << (2 * (4 * j3 + 0));
                pk |= (unsigned)(yv.y & 3) << (2 * (4 * j3 + 1));
                pk |= (unsigned)(yv.z & 3) << (2 * (4 * j3 + 2));
                pk |= (unsigned)(yv.w & 3) << (2 * (4 * j3 + 3));
            }
            yb[i] = pk;
        }
        __syncthreads();
    }

    float lsum = 0.f;

    // ---- T14 prefetch registers: class-0 A-window loaded in the prologue ----
    __half2 v2[IW];
    if (PRE && actA) {
        const __half* xc0 = xs + (size_t)(4 * b) * (size_t)CSTRIDE;
#pragma unroll
        for (int iw = 0; iw < IW; iw++)
            v2[iw] = *(const __half2*)(xc0 + goff[iw]);
    }

#pragma unroll
    for (int cl = 0; cl < 4; cl++) {
        if (!PRE) {
            stageF(cl);
            __syncthreads();   // vsF(cl) ready (fallback only)
            if (actA) {
#pragma unroll
                for (int iw = 0; iw < IW; iw++)
                    v2[iw] = *(const __half2*)&vsF[(ihA * IW + iw) * IDS + sA_];
            }
        }

        // ---- Phase A: W-window over prefetched v2. 210 items (ih,dp) ----
        if (actA) {
            const __half2 z2 = __float2half2_rn(0.f);
            __half2 sm = z2, sp = z2, sq = z2;
#pragma unroll
            for (int iw = 0; iw < WINS; iw++) {
                __half2 p, m;
                pmask(v2[iw], p, m);
                sm = __hadd2(sm, m);
                sp = __hadd2(sp, p);
                sq = __hfma2(p, v2[iw], sq);
            }
            int o = slA0;
            sA01[o] = make_uint2(h2u(sm), h2u(sp));
            sA2v[o] = sq;
#pragma unroll
            for (int wo = 1; wo < TW; wo++) {
                const __half2 a = v2[wo + 6], bb = v2[wo - 1];
                __half2 pa, ma, pb, mb;
                pmask(a, pa, ma);
                pmask(bb, pb, mb);
                sm = __hadd2(sm, __hsub2(ma, mb));
                sp = __hadd2(sp, __hsub2(pa, pb));
                sq = __hadd2(sq, __hsub2(__hmul2(pa, a), __hmul2(pb, bb)));
                o += NDP;
                sA01[o] = make_uint2(h2u(sm), h2u(sp));
                sA2v[o] = sq;
            }
            // ---- Issue class cl+1 loads NOW (v2 consumed): they land
            // during barA + B + barB + C instead of stalling next A.
            if (PRE && cl < 3) {
                const __half* xcn =
                    xs + (size_t)(4 * b + cl + 1) * (size_t)CSTRIDE;
#pragma unroll
                for (int iw = 0; iw < IW; iw++)
                    v2[iw] = *(const __half2*)(xcn + goff[iw]);
            }
        }
        __syncthreads();   // barA: sA ready; C(cl-1) sb-reads retired

        // ---- Phase B: H-window. 240 items ----
        if (actB) {
            __half2 a0[10], a1[10], a2[10];
#pragma unroll
            for (int k = 0; k < 10; k++) {
                const int idx = slB0 + k * (TW * NDP);
                const uint2 v01 = sA01[idx];
                a0[k] = u2h(v01.x);
                a1[k] = u2h(v01.y);
                a2[k] = sA2v[idx];
            }
            __half2 s0 = a0[0], s1 = a1[0], s2 = a2[0];
#pragma unroll
            for (int k = 1; k < WINS; k++) {
                s0 = __hadd2(s0, a0[k]);
                s1 = __hadd2(s1, a1[k]);
                s2 = __hadd2(s2, a2[k]);
            }
            int o = slB0;
            sb01[o] = make_uint2(h2u(s0), h2u(s1));
            sb2v[o] = s2;
#pragma unroll
            for (int k = 1; k < 4; k++) {
                s0 = __hadd2(s0, __hsub2(a0[k + 6], a0[k - 1]));
                s1 = __hadd2(s1, __hsub2(a1[k + 6], a1[k - 1]));
                s2 = __hadd2(s2, __hsub2(a2[k + 6], a2[k - 1]));
                o += TW * NDP;
                sb01[o] = make_uint2(h2u(s0), h2u(s1));
                sb2v[o] = s2;
            }
        }
        __syncthreads();   // barB: sb ready; B sA-reads retired before next A

        // ---- Phase C: D-window, 6 outputs per thread (ho,wo,dq) ----
        if (actC) {
            float b0[12], b1[12], b2[12];
#pragma unroll
            for (int k = 0; k < 6; k++) {
                const uint2 v01 = sb01[slC0 + k];
                float2 f;
                f = __half22float2(u2h(v01.x));
                b0[2 * k] = f.x; b0[2 * k + 1] = f.y;
                f = __half22float2(u2h(v01.y));
                b1[2 * k] = f.x; b1[2 * k + 1] = f.y;
                f = __half22float2(sb2v[slC0 + k]);
                b2[2 * k] = f.x; b2[2 * k + 1] = f.y;
            }
            float s0 = 0.f, s1 = 0.f, s2 = 0.f;
#pragma unroll
            for (int k = 0; k < WINS; k++) { s0 += b0[k]; s1 += b1[k]; s2 += b2[k]; }
            const int od0 = 6 * dqC;
#pragma unroll
            for (int k = 0; k < 6; k++) {
                if (k > 0) {
                    s0 += b0[k + 6] - b0[k - 1];
                    s1 += b1[k + 6] - b1[k - 1];
                    s2 += b2[k + 6] - b2[k - 1];
                }
                if (od0 + k < odmax) lsum += sval(s0, s1, s2);
            }
        }
        // no trailing barrier: next barA separates C's sb-reads from B(cl+1)
    }

    // wave(64) shuffle reduce, then cross-wave via LDS, one atomic per block
#pragma unroll
    for (int off = 32; off > 0; off >>= 1) lsum += __shfl_down(lsum, off, 64);
    const int wave = t >> 6;
    if ((t & 63) == 0) wsum[wave] = lsum;
    __syncthreads();
    if (t == 0) {
        const float s = wsum[0] + wsum[1] + wsum[2] + wsum[3];
        atomicAdd(acc, (double)s);
    }
}

__global__ void structure_loss_finalize(const double* __restrict__ acc,
                                        float* __restrict__ out) {
    out[0] = 1.0f - (float)(acc[0] / 17075520.0);   // 8*154*154*90
}

extern "C" void kernel_launch(void* const* d_in, const int* in_sizes, int n_in,
                              void* d_out, int out_size, void* d_ws, size_t ws_size,
                              hipStream_t stream) {
    const float* x = (const float*)d_in[0];
    const int*   y = (const int*)d_in[1];
    double* acc = (double*)d_ws;
    __half* xs = (__half*)((char*)d_ws + 16);

    const size_t need = 16 + (size_t)8 * CSTRIDE * sizeof(__half);   // ~39.3 MB
    dim3 grid(DTILES, WTILES, 2 * HTILES);   // (4, 20, 40) = 3,200 blocks

    if (ws_size >= need) {
        // prepass zeroes acc -> 3 dispatches total
        sigmoid_prepass<<<dim3(2400, 2), 256, 0, stream>>>(x, y, xs, acc);
        structure_loss_main<true><<<grid, 256, 0, stream>>>(x, y, xs, acc);
    } else {
        (void)hipMemsetAsync(d_ws, 0, sizeof(double), stream);
        structure_loss_main<false><<<grid, 256, 0, stream>>>(x, y, xs, acc);
    }
    structure_loss_finalize<<<1, 1, 0, stream>>>(acc, (float*)d_out);
}